// Round 1
// baseline (336.303 us; speedup 1.0000x reference)
//
#include <hip/hip_runtime.h>
#include <math.h>

#define NP 16
#define NB 512
#define ND 2048
#define NM (NP*NB)          // 8192 rows
#define BK 16

static constexpr float INV_TEMP = 5.0f;   // 1 / 0.2

// ---------------------------------------------------------------- z_sum ----
// z_sum[b*ND+d] = sum_p feat[p][b][d]; float4 over the (b,d) plane.
__global__ void zsum_kernel(const float4* __restrict__ feat,
                            float4* __restrict__ zsum) {
    int i = blockIdx.x * blockDim.x + threadIdx.x;   // < NB*ND/4
    float4 s = make_float4(0.f, 0.f, 0.f, 0.f);
#pragma unroll
    for (int p = 0; p < NP; ++p) {
        float4 v = feat[(size_t)p * (NB * ND / 4) + i];
        s.x += v.x; s.y += v.y; s.z += v.z; s.w += v.w;
    }
    zsum[i] = s;
}

// ------------------------------------------------------------- row norms ---
// invn[row] = 1 / max(||x_row||, 1e-12); one 256-thread block per row of ND.
__global__ void rownorm_kernel(const float* __restrict__ x,
                               float* __restrict__ invn) {
    int row = blockIdx.x;
    const float4* r = (const float4*)(x + (size_t)row * ND);
    float s = 0.f;
#pragma unroll
    for (int it = 0; it < 2; ++it) {                 // ND/4 = 512 = 2*256
        float4 v = r[threadIdx.x + it * 256];
        s += v.x * v.x + v.y * v.y + v.z * v.z + v.w * v.w;
    }
#pragma unroll
    for (int off = 32; off > 0; off >>= 1) s += __shfl_down(s, off);
    __shared__ float wsum[4];
    int lane = threadIdx.x & 63, wid = threadIdx.x >> 6;
    if (lane == 0) wsum[wid] = s;
    __syncthreads();
    if (threadIdx.x == 0) {
        float t = wsum[0] + wsum[1] + wsum[2] + wsum[3];
        invn[row] = 1.f / fmaxf(sqrtf(t), 1e-12f);
    }
}

// ------------------------------------------------- GEMM + fused CE loss ----
// Block: 16 rows x 512 cols. 256 threads = 4 waves; wave ty owns rows
// ty*4..ty*4+3; lane tx owns cols {tx*4..tx*4+3, 256+tx*4..+3}.
__global__ __launch_bounds__(256) void gemm_loss_kernel(
        const float* __restrict__ feat,   // [NM][ND]
        const float* __restrict__ zsum,   // [NB][ND]
        const float* __restrict__ invf,   // [NM]
        const float* __restrict__ invz,   // [NB]
        float* __restrict__ loss_acc) {
    __shared__ float a_lds[BK][20];       // [kk][row], pitch 20 (16B-aligned)
    __shared__ float b_lds[BK][516];      // [kk][col], pitch 516 (16B-aligned)

    const int tid  = threadIdx.x;
    const int tx   = tid & 63;
    const int ty   = tid >> 6;
    const int brow = blockIdx.x * 16;

    float acc[4][8];
#pragma unroll
    for (int r = 0; r < 4; ++r)
#pragma unroll
        for (int c = 0; c < 8; ++c) acc[r][c] = 0.f;

    for (int k0 = 0; k0 < ND; k0 += BK) {
        // stage A tile (16 rows x BK), transposed to [kk][row]
        if (tid < 64) {
            int row = tid >> 2, q = tid & 3;
            float4 v = *(const float4*)(feat + (size_t)(brow + row) * ND + k0 + q * 4);
            a_lds[q * 4 + 0][row] = v.x; a_lds[q * 4 + 1][row] = v.y;
            a_lds[q * 4 + 2][row] = v.z; a_lds[q * 4 + 3][row] = v.w;
        }
        // stage B tile (512 cols x BK), transposed to [kk][col]
#pragma unroll
        for (int u = 0; u < 8; ++u) {
            int chunk = u * 256 + tid;            // < 2048
            int col = chunk >> 2, q = chunk & 3;
            float4 v = *(const float4*)(zsum + (size_t)col * ND + k0 + q * 4);
            b_lds[q * 4 + 0][col] = v.x; b_lds[q * 4 + 1][col] = v.y;
            b_lds[q * 4 + 2][col] = v.z; b_lds[q * 4 + 3][col] = v.w;
        }
        __syncthreads();
#pragma unroll
        for (int kk = 0; kk < BK; ++kk) {
            float4 av = *(const float4*)&a_lds[kk][ty * 4];
            float4 b0 = *(const float4*)&b_lds[kk][tx * 4];
            float4 b1 = *(const float4*)&b_lds[kk][256 + tx * 4];
            float a[4]  = {av.x, av.y, av.z, av.w};
            float bb[8] = {b0.x, b0.y, b0.z, b0.w, b1.x, b1.y, b1.z, b1.w};
#pragma unroll
            for (int r = 0; r < 4; ++r)
#pragma unroll
                for (int c = 0; c < 8; ++c)
                    acc[r][c] = fmaf(a[r], bb[c], acc[r][c]);
        }
        __syncthreads();
    }

    // epilogue: sim = dot * invf[row] * invz[col]; per-row logsumexp - pos
    float izc[8];
#pragma unroll
    for (int g = 0; g < 2; ++g)
#pragma unroll
        for (int j = 0; j < 4; ++j)
            izc[g * 4 + j] = invz[g * 256 + tx * 4 + j];

    float local = 0.f;
#pragma unroll
    for (int r = 0; r < 4; ++r) {
        int grow = brow + ty * 4 + r;
        float sf = invf[grow];
        float l[8];
        float mx = -1e30f;
#pragma unroll
        for (int c = 0; c < 8; ++c) {
            float li = acc[r][c] * sf * izc[c] * INV_TEMP;
            l[c] = li;
            mx = fmaxf(mx, li);
        }
#pragma unroll
        for (int off = 32; off > 0; off >>= 1) mx = fmaxf(mx, __shfl_xor(mx, off));
        float se = 0.f;
#pragma unroll
        for (int c = 0; c < 8; ++c) se += __expf(l[c] - mx);
#pragma unroll
        for (int off = 32; off > 0; off >>= 1) se += __shfl_xor(se, off);

        int pcol = grow & (NB - 1);               // row % 512
        int pg = pcol >> 8, prem = pcol & 255;
        int ptx = prem >> 2, pj = prem & 3;
        int pidx = pg * 4 + pj;                   // wave-uniform
        float myl = l[0];
#pragma unroll
        for (int c = 1; c < 8; ++c) myl = (c == pidx) ? l[c] : myl;  // static idx, no scratch
        float posl = __shfl(myl, ptx);

        local += (mx + __logf(se)) - posl;
    }
    if (tx == 0) atomicAdd(loss_acc, local);
}

__global__ void finalize_kernel(const float* __restrict__ acc,
                                float* __restrict__ out) {
    out[0] = acc[0] * (1.0f / (float)NM);
}

extern "C" void kernel_launch(void* const* d_in, const int* in_sizes, int n_in,
                              void* d_out, int out_size, void* d_ws, size_t ws_size,
                              hipStream_t stream) {
    const float* feat = (const float*)d_in[0];

    float* zsum = (float*)d_ws;            // NB*ND floats = 4 MB
    float* invf = zsum + (size_t)NB * ND;  // NM floats
    float* invz = invf + NM;               // NB floats
    float* lacc = invz + NB;               // 1 float

    hipMemsetAsync(lacc, 0, sizeof(float), stream);

    zsum_kernel<<<(NB * ND / 4) / 256, 256, 0, stream>>>(
        (const float4*)feat, (float4*)zsum);
    rownorm_kernel<<<NM, 256, 0, stream>>>(feat, invf);
    rownorm_kernel<<<NB, 256, 0, stream>>>(zsum, invz);
    gemm_loss_kernel<<<NM / 16, 256, 0, stream>>>(feat, zsum, invf, invz, lacc);
    finalize_kernel<<<1, 1, 0, stream>>>(lacc, (float*)d_out);
}

// Round 2
// 143.258 us; speedup vs baseline: 2.3475x; 2.3475x over previous
//
#include <hip/hip_runtime.h>
#include <hip/hip_bf16.h>
#include <math.h>

#define NP 16
#define NB 512
#define ND 2048
#define NM (NP*NB)          // 8192 rows

typedef __attribute__((ext_vector_type(8))) short bf16x8;
typedef __attribute__((ext_vector_type(4))) float f32x4;

__device__ inline unsigned short f2bf(float f) {
    unsigned u = __float_as_uint(f);
    unsigned r = (u + 0x7fffu + ((u >> 16) & 1u)) >> 16;   // RNE
    return (unsigned short)r;
}

// ---------------------------------------------------------------------------
// Fused: z_sum over patches + row L2 norm + write pre-normalized bf16 z.
// One 256-thread block per batch row b. Reads 16 rows of 8KB (coalesced),
// writes 4KB bf16.
__global__ __launch_bounds__(256) void zsum_norm_kernel(
        const float* __restrict__ feat, unsigned short* __restrict__ zn) {
    const int b = blockIdx.x, tid = threadIdx.x;
    const float4* base = (const float4*)feat + (size_t)b * (ND / 4);
    float4 s0 = {0,0,0,0}, s1 = {0,0,0,0};
#pragma unroll
    for (int p = 0; p < NP; ++p) {
        const float4* bp = base + (size_t)p * (NB * ND / 4);
        float4 v0 = bp[tid], v1 = bp[256 + tid];
        s0.x += v0.x; s0.y += v0.y; s0.z += v0.z; s0.w += v0.w;
        s1.x += v1.x; s1.y += v1.y; s1.z += v1.z; s1.w += v1.w;
    }
    float ss = s0.x*s0.x + s0.y*s0.y + s0.z*s0.z + s0.w*s0.w
             + s1.x*s1.x + s1.y*s1.y + s1.z*s1.z + s1.w*s1.w;
#pragma unroll
    for (int off = 32; off > 0; off >>= 1) ss += __shfl_xor(ss, off);
    __shared__ float wpart[4];
    __shared__ float invz_s;
    int lane = tid & 63, wv = tid >> 6;
    if (lane == 0) wpart[wv] = ss;
    __syncthreads();
    if (tid == 0)
        invz_s = 1.f / fmaxf(sqrtf(wpart[0] + wpart[1] + wpart[2] + wpart[3]), 1e-12f);
    __syncthreads();
    float iz = invz_s;
    ushort4 o0, o1;
    o0.x = f2bf(s0.x * iz); o0.y = f2bf(s0.y * iz);
    o0.z = f2bf(s0.z * iz); o0.w = f2bf(s0.w * iz);
    o1.x = f2bf(s1.x * iz); o1.y = f2bf(s1.y * iz);
    o1.z = f2bf(s1.z * iz); o1.w = f2bf(s1.w * iz);
    ((ushort4*)(zn + (size_t)b * ND))[tid] = o0;
    ((ushort4*)(zn + (size_t)b * ND + 1024))[tid] = o1;
}

// ---------------------------------------------------------------------------
// Register MFMA GEMM + fused CE loss. Block = 32 rows x 512 cols, 8 waves,
// wave w owns cols [w*64, w*64+64). No LDS in the K-loop; B (zn, 2MB bf16)
// is L2-resident, A is read fp32 and converted inline (sumsq fused -> invf).
__global__ __launch_bounds__(512) void gemm_loss_kernel(
        const float* __restrict__ feat,       // [NM][ND] fp32
        const unsigned short* __restrict__ zn,// [NB][ND] bf16, pre-normalized
        float* __restrict__ loss_acc) {
    const int tid  = threadIdx.x;
    const int lane = tid & 63;
    const int w    = tid >> 6;       // wave 0..7
    const int l15  = lane & 15;
    const int l4   = lane >> 4;      // 0..3
    const int brow = blockIdx.x * 32;
    const int bcol = w * 64;

    f32x4 acc[2][4] = {};
    float ssq0 = 0.f, ssq1 = 0.f;

    const float* a0p = feat + (size_t)(brow + l15) * ND + l4 * 8;
    const float* a1p = a0p + (size_t)16 * ND;
    const short* bp0 = (const short*)zn + (size_t)(bcol + l15) * ND + l4 * 8;

#pragma unroll 4
    for (int s = 0; s < ND / 32; ++s) {
        const int ko = s * 32;
        float4 a0lo = *(const float4*)(a0p + ko);
        float4 a0hi = *(const float4*)(a0p + ko + 4);
        float4 a1lo = *(const float4*)(a1p + ko);
        float4 a1hi = *(const float4*)(a1p + ko + 4);

        bf16x8 bfr[4];
#pragma unroll
        for (int n = 0; n < 4; ++n)
            bfr[n] = *(const bf16x8*)(bp0 + (size_t)n * 16 * ND + ko);

        ssq0 += a0lo.x*a0lo.x + a0lo.y*a0lo.y + a0lo.z*a0lo.z + a0lo.w*a0lo.w
              + a0hi.x*a0hi.x + a0hi.y*a0hi.y + a0hi.z*a0hi.z + a0hi.w*a0hi.w;
        ssq1 += a1lo.x*a1lo.x + a1lo.y*a1lo.y + a1lo.z*a1lo.z + a1lo.w*a1lo.w
              + a1hi.x*a1hi.x + a1hi.y*a1hi.y + a1hi.z*a1hi.z + a1hi.w*a1hi.w;

        bf16x8 af0, af1;
        af0[0] = (short)f2bf(a0lo.x); af0[1] = (short)f2bf(a0lo.y);
        af0[2] = (short)f2bf(a0lo.z); af0[3] = (short)f2bf(a0lo.w);
        af0[4] = (short)f2bf(a0hi.x); af0[5] = (short)f2bf(a0hi.y);
        af0[6] = (short)f2bf(a0hi.z); af0[7] = (short)f2bf(a0hi.w);
        af1[0] = (short)f2bf(a1lo.x); af1[1] = (short)f2bf(a1lo.y);
        af1[2] = (short)f2bf(a1lo.z); af1[3] = (short)f2bf(a1lo.w);
        af1[4] = (short)f2bf(a1hi.x); af1[5] = (short)f2bf(a1hi.y);
        af1[6] = (short)f2bf(a1hi.z); af1[7] = (short)f2bf(a1hi.w);

#pragma unroll
        for (int n = 0; n < 4; ++n) {
            acc[0][n] = __builtin_amdgcn_mfma_f32_16x16x32_bf16(af0, bfr[n], acc[0][n], 0, 0, 0);
            acc[1][n] = __builtin_amdgcn_mfma_f32_16x16x32_bf16(af1, bfr[n], acc[1][n], 0, 0, 0);
        }
    }

    // row sums-of-squares: lanes {l, l^16, l^32, l^48} cover a full row
    ssq0 += __shfl_xor(ssq0, 16); ssq0 += __shfl_xor(ssq0, 32);
    ssq1 += __shfl_xor(ssq1, 16); ssq1 += __shfl_xor(ssq1, 32);

    __shared__ float sm_ssq[32];
    __shared__ float sm_max[32][8];
    __shared__ float sm_sum[32][8];
    __shared__ float sm_pos[32];
    if (tid < 16) { sm_ssq[tid] = ssq0; sm_ssq[16 + tid] = ssq1; }
    __syncthreads();

#pragma unroll
    for (int m = 0; m < 2; ++m) {
#pragma unroll
        for (int r = 0; r < 4; ++r) {
            const int row = m * 16 + l4 * 4 + r;        // local D row
            const float invf = 1.f / fmaxf(sqrtf(sm_ssq[row]), 1e-12f);
            float lg[4];
            float mx = -1e30f;
#pragma unroll
            for (int n = 0; n < 4; ++n) {
                lg[n] = acc[m][n][r] * invf * 5.0f;     // /TEMP
                mx = fmaxf(mx, lg[n]);
            }
            mx = fmaxf(mx, __shfl_xor(mx, 1));
            mx = fmaxf(mx, __shfl_xor(mx, 2));
            mx = fmaxf(mx, __shfl_xor(mx, 4));
            mx = fmaxf(mx, __shfl_xor(mx, 8));
            float se = 0.f;
#pragma unroll
            for (int n = 0; n < 4; ++n) se += __expf(lg[n] - mx);
            se += __shfl_xor(se, 1);
            se += __shfl_xor(se, 2);
            se += __shfl_xor(se, 4);
            se += __shfl_xor(se, 8);
            if (l15 == 0) { sm_max[row][w] = mx; sm_sum[row][w] = se; }
            const int posc = (brow + row) & (NB - 1);   // row % 512
#pragma unroll
            for (int n = 0; n < 4; ++n)
                if (bcol + n * 16 + l15 == posc) sm_pos[row] = lg[n];
        }
    }
    __syncthreads();

    if (tid < 32) {
        const int row = tid;
        float gm = -1e30f;
#pragma unroll
        for (int wv = 0; wv < 8; ++wv) gm = fmaxf(gm, sm_max[row][wv]);
        float tot = 0.f;
#pragma unroll
        for (int wv = 0; wv < 8; ++wv)
            tot += sm_sum[row][wv] * __expf(sm_max[row][wv] - gm);
        float term = gm + __logf(tot) - sm_pos[row];
        term += __shfl_xor(term, 16);
        term += __shfl_xor(term, 8);
        term += __shfl_xor(term, 4);
        term += __shfl_xor(term, 2);
        term += __shfl_xor(term, 1);
        if (tid == 0) atomicAdd(loss_acc, term);
    }
}

__global__ void finalize_kernel(const float* __restrict__ acc,
                                float* __restrict__ out) {
    out[0] = acc[0] * (1.0f / (float)NM);
}

extern "C" void kernel_launch(void* const* d_in, const int* in_sizes, int n_in,
                              void* d_out, int out_size, void* d_ws, size_t ws_size,
                              hipStream_t stream) {
    const float* feat = (const float*)d_in[0];

    unsigned short* zn = (unsigned short*)d_ws;            // NB*ND bf16 = 2 MB
    float* lacc = (float*)(zn + (size_t)NB * ND);          // 1 float

    hipMemsetAsync(lacc, 0, sizeof(float), stream);

    zsum_norm_kernel<<<NB, 256, 0, stream>>>(feat, zn);
    gemm_loss_kernel<<<NM / 32, 512, 0, stream>>>(feat, zn, lacc);
    finalize_kernel<<<1, 1, 0, stream>>>(lacc, (float*)d_out);
}

// Round 3
// 118.899 us; speedup vs baseline: 2.8285x; 1.2049x over previous
//
#include <hip/hip_runtime.h>
#include <hip/hip_bf16.h>
#include <math.h>

#define NP 16
#define NB 512
#define ND 2048
#define NM (NP*NB)          // 8192 rows

typedef __attribute__((ext_vector_type(8))) short bf16x8;
typedef __attribute__((ext_vector_type(4))) float f32x4;

__device__ inline unsigned short f2bf(float f) {
    unsigned u = __float_as_uint(f);
    unsigned r = (u + 0x7fffu + ((u >> 16) & 1u)) >> 16;   // RNE
    return (unsigned short)r;
}

__device__ inline float dot4(float4 v) {
    return v.x * v.x + v.y * v.y + v.z * v.z + v.w * v.w;
}

// ---------------------------------------------------------------------------
// Prep: one pass over feat. Per block b (512 blocks, 256 thr = 4 waves):
//  - wave wv fully processes patches p = wv*4 .. wv*4+3:
//      row ssq (wave shfl-reduce) -> write pre-normalized bf16 A row
//      accumulate per-wave partial z-sum (32 f32/lane)
//  - cross-wave z-sum via LDS, z ssq block-reduce, write pre-normalized zn.
__global__ __launch_bounds__(256) void prep_kernel(
        const float* __restrict__ feat,
        unsigned short* __restrict__ an,     // [NM][ND] bf16, row-normalized
        unsigned short* __restrict__ zn) {   // [NB][ND] bf16, row-normalized
    const int b = blockIdx.x, tid = threadIdx.x;
    const int lane = tid & 63, wv = tid >> 6;
    const float4* feat4 = (const float4*)feat;

    float4 zp[8];
#pragma unroll
    for (int it = 0; it < 8; ++it) zp[it] = make_float4(0.f, 0.f, 0.f, 0.f);

#pragma unroll
    for (int j = 0; j < 4; ++j) {
        const int p = wv * 4 + j;
        const size_t row = (size_t)p * NB + b;
        const float4* rp = feat4 + row * (ND / 4);
        float4 rv[8];
        float ss = 0.f;
#pragma unroll
        for (int it = 0; it < 8; ++it) {
            rv[it] = rp[it * 64 + lane];
            ss += dot4(rv[it]);
            zp[it].x += rv[it].x; zp[it].y += rv[it].y;
            zp[it].z += rv[it].z; zp[it].w += rv[it].w;
        }
#pragma unroll
        for (int off = 32; off > 0; off >>= 1) ss += __shfl_xor(ss, off);
        const float inv = 1.f / fmaxf(sqrtf(ss), 1e-12f);
        ushort4* wp = (ushort4*)(an + row * ND);
#pragma unroll
        for (int it = 0; it < 8; ++it) {
            ushort4 o;
            o.x = f2bf(rv[it].x * inv); o.y = f2bf(rv[it].y * inv);
            o.z = f2bf(rv[it].z * inv); o.w = f2bf(rv[it].w * inv);
            wp[it * 64 + lane] = o;
        }
    }

    __shared__ float4 zl[4][512];        // 32 KB
#pragma unroll
    for (int it = 0; it < 8; ++it) zl[wv][it * 64 + lane] = zp[it];
    __syncthreads();

    float4 z0 = zl[0][tid];
    float4 z1 = zl[0][tid + 256];
    {
        float4 a = zl[1][tid], c = zl[2][tid], d = zl[3][tid];
        z0.x += a.x + c.x + d.x; z0.y += a.y + c.y + d.y;
        z0.z += a.z + c.z + d.z; z0.w += a.w + c.w + d.w;
        float4 e = zl[1][tid + 256], f = zl[2][tid + 256], g = zl[3][tid + 256];
        z1.x += e.x + f.x + g.x; z1.y += e.y + f.y + g.y;
        z1.z += e.z + f.z + g.z; z1.w += e.w + f.w + g.w;
    }
    float ss = dot4(z0) + dot4(z1);
#pragma unroll
    for (int off = 32; off > 0; off >>= 1) ss += __shfl_xor(ss, off);
    __shared__ float wpart[4];
    __shared__ float invz_s;
    if (lane == 0) wpart[wv] = ss;
    __syncthreads();
    if (tid == 0)
        invz_s = 1.f / fmaxf(sqrtf(wpart[0] + wpart[1] + wpart[2] + wpart[3]), 1e-12f);
    __syncthreads();
    const float iz = invz_s;
    ushort4 o0, o1;
    o0.x = f2bf(z0.x * iz); o0.y = f2bf(z0.y * iz);
    o0.z = f2bf(z0.z * iz); o0.w = f2bf(z0.w * iz);
    o1.x = f2bf(z1.x * iz); o1.y = f2bf(z1.y * iz);
    o1.z = f2bf(z1.z * iz); o1.w = f2bf(z1.w * iz);
    ((ushort4*)(zn + (size_t)b * ND))[tid] = o0;
    ((ushort4*)(zn + (size_t)b * ND))[tid + 256] = o1;
}

// ---------------------------------------------------------------------------
// GEMM + fused CE loss, all-bf16 operands (pre-normalized). Block = 32 rows x
// 512 cols, 8 waves; wave w owns cols [w*64, w*64+64), acc 2x4 f32x4.
// Per K=32 step: 2 A-loads + 4 B-loads (16B each) + 8 MFMA. No LDS, no cvt.
__global__ __launch_bounds__(512) void gemm_loss_kernel(
        const unsigned short* __restrict__ an, // [NM][ND] bf16
        const unsigned short* __restrict__ zn, // [NB][ND] bf16
        float* __restrict__ loss_acc) {
    const int tid  = threadIdx.x;
    const int lane = tid & 63;
    const int w    = tid >> 6;
    const int l15  = lane & 15;
    const int l4   = lane >> 4;
    const int brow = blockIdx.x * 32;
    const int bcol = w * 64;

    const short* ap = (const short*)an + (size_t)(brow + l15) * ND + l4 * 8;
    const short* bp = (const short*)zn + (size_t)(bcol + l15) * ND + l4 * 8;

    f32x4 acc[2][4] = {};

#pragma unroll 8
    for (int s = 0; s < ND / 32; ++s) {
        const int ko = s * 32;
        bf16x8 a0 = *(const bf16x8*)(ap + ko);
        bf16x8 a1 = *(const bf16x8*)(ap + (size_t)16 * ND + ko);
        bf16x8 bfr[4];
#pragma unroll
        for (int n = 0; n < 4; ++n)
            bfr[n] = *(const bf16x8*)(bp + (size_t)n * 16 * ND + ko);
#pragma unroll
        for (int n = 0; n < 4; ++n) {
            acc[0][n] = __builtin_amdgcn_mfma_f32_16x16x32_bf16(a0, bfr[n], acc[0][n], 0, 0, 0);
            acc[1][n] = __builtin_amdgcn_mfma_f32_16x16x32_bf16(a1, bfr[n], acc[1][n], 0, 0, 0);
        }
    }

    // ---- epilogue: logits = acc * (1/TEMP); per-row logsumexp - pos ----
    __shared__ float sm_max[32][8];
    __shared__ float sm_sum[32][8];
    __shared__ float sm_pos[32];

#pragma unroll
    for (int m = 0; m < 2; ++m) {
#pragma unroll
        for (int r = 0; r < 4; ++r) {
            const int row = m * 16 + l4 * 4 + r;        // local row 0..31
            float lg[4];
            float mx = -1e30f;
#pragma unroll
            for (int n = 0; n < 4; ++n) {
                lg[n] = acc[m][n][r] * 5.0f;            // /TEMP
                mx = fmaxf(mx, lg[n]);
            }
            mx = fmaxf(mx, __shfl_xor(mx, 1));
            mx = fmaxf(mx, __shfl_xor(mx, 2));
            mx = fmaxf(mx, __shfl_xor(mx, 4));
            mx = fmaxf(mx, __shfl_xor(mx, 8));
            float se = 0.f;
#pragma unroll
            for (int n = 0; n < 4; ++n) se += __expf(lg[n] - mx);
            se += __shfl_xor(se, 1);
            se += __shfl_xor(se, 2);
            se += __shfl_xor(se, 4);
            se += __shfl_xor(se, 8);
            if (l15 == 0) { sm_max[row][w] = mx; sm_sum[row][w] = se; }
            const int posc = (brow + row) & (NB - 1);   // global row % 512
#pragma unroll
            for (int n = 0; n < 4; ++n)
                if (bcol + n * 16 + l15 == posc) sm_pos[row] = lg[n];
        }
    }
    __syncthreads();

    if (tid < 32) {
        const int row = tid;
        float gm = -1e30f;
#pragma unroll
        for (int wv = 0; wv < 8; ++wv) gm = fmaxf(gm, sm_max[row][wv]);
        float tot = 0.f;
#pragma unroll
        for (int wv = 0; wv < 8; ++wv)
            tot += sm_sum[row][wv] * __expf(sm_max[row][wv] - gm);
        float term = gm + __logf(tot) - sm_pos[row];
        term += __shfl_xor(term, 16);
        term += __shfl_xor(term, 8);
        term += __shfl_xor(term, 4);
        term += __shfl_xor(term, 2);
        term += __shfl_xor(term, 1);
        if (tid == 0) atomicAdd(loss_acc, term);
    }
}

__global__ void finalize_kernel(const float* __restrict__ acc,
                                float* __restrict__ out) {
    out[0] = acc[0] * (1.0f / (float)NM);
}

extern "C" void kernel_launch(void* const* d_in, const int* in_sizes, int n_in,
                              void* d_out, int out_size, void* d_ws, size_t ws_size,
                              hipStream_t stream) {
    const float* feat = (const float*)d_in[0];

    unsigned short* an = (unsigned short*)d_ws;            // 8192*2048 bf16 = 32 MB
    unsigned short* zn = an + (size_t)NM * ND;             // 512*2048 bf16 = 2 MB
    float* lacc = (float*)(zn + (size_t)NB * ND);          // 1 float

    hipMemsetAsync(lacc, 0, sizeof(float), stream);

    prep_kernel<<<NB, 256, 0, stream>>>(feat, an, zn);
    gemm_loss_kernel<<<NM / 32, 512, 0, stream>>>(an, zn, lacc);
    finalize_kernel<<<1, 1, 0, stream>>>(lacc, (float*)d_out);
}

// Round 4
// 118.373 us; speedup vs baseline: 2.8410x; 1.0044x over previous
//
#include <hip/hip_runtime.h>
#include <hip/hip_bf16.h>
#include <math.h>

#define NP 16
#define NB 512
#define ND 2048
#define NM (NP*NB)          // 8192 rows

typedef __attribute__((ext_vector_type(8))) short bf16x8;
typedef __attribute__((ext_vector_type(4))) float f32x4;

__device__ inline unsigned short f2bf(float f) {
    unsigned u = __float_as_uint(f);
    unsigned r = (u + 0x7fffu + ((u >> 16) & 1u)) >> 16;   // RNE
    return (unsigned short)r;
}

__device__ inline float dot4(float4 v) {
    return v.x * v.x + v.y * v.y + v.z * v.z + v.w * v.w;
}

// ---------------------------------------------------------------------------
// Prep: one pass over feat. Per block b (512 blocks, 256 thr = 4 waves):
// row-normalized bf16 A rows + z-sum -> normalized bf16 zn row.
__global__ __launch_bounds__(256) void prep_kernel(
        const float* __restrict__ feat,
        unsigned short* __restrict__ an,     // [NM][ND] bf16, row-normalized
        unsigned short* __restrict__ zn) {   // [NB][ND] bf16, row-normalized
    const int b = blockIdx.x, tid = threadIdx.x;
    const int lane = tid & 63, wv = tid >> 6;
    const float4* feat4 = (const float4*)feat;

    float4 zp[8];
#pragma unroll
    for (int it = 0; it < 8; ++it) zp[it] = make_float4(0.f, 0.f, 0.f, 0.f);

#pragma unroll
    for (int j = 0; j < 4; ++j) {
        const int p = wv * 4 + j;
        const size_t row = (size_t)p * NB + b;
        const float4* rp = feat4 + row * (ND / 4);
        float4 rv[8];
        float ss = 0.f;
#pragma unroll
        for (int it = 0; it < 8; ++it) {
            rv[it] = rp[it * 64 + lane];
            ss += dot4(rv[it]);
            zp[it].x += rv[it].x; zp[it].y += rv[it].y;
            zp[it].z += rv[it].z; zp[it].w += rv[it].w;
        }
#pragma unroll
        for (int off = 32; off > 0; off >>= 1) ss += __shfl_xor(ss, off);
        const float inv = 1.f / fmaxf(sqrtf(ss), 1e-12f);
        ushort4* wp = (ushort4*)(an + row * ND);
#pragma unroll
        for (int it = 0; it < 8; ++it) {
            ushort4 o;
            o.x = f2bf(rv[it].x * inv); o.y = f2bf(rv[it].y * inv);
            o.z = f2bf(rv[it].z * inv); o.w = f2bf(rv[it].w * inv);
            wp[it * 64 + lane] = o;
        }
    }

    __shared__ float4 zl[4][512];        // 32 KB
#pragma unroll
    for (int it = 0; it < 8; ++it) zl[wv][it * 64 + lane] = zp[it];
    __syncthreads();

    float4 z0 = zl[0][tid];
    float4 z1 = zl[0][tid + 256];
    {
        float4 a = zl[1][tid], c = zl[2][tid], d = zl[3][tid];
        z0.x += a.x + c.x + d.x; z0.y += a.y + c.y + d.y;
        z0.z += a.z + c.z + d.z; z0.w += a.w + c.w + d.w;
        float4 e = zl[1][tid + 256], f = zl[2][tid + 256], g = zl[3][tid + 256];
        z1.x += e.x + f.x + g.x; z1.y += e.y + f.y + g.y;
        z1.z += e.z + f.z + g.z; z1.w += e.w + f.w + g.w;
    }
    float ss = dot4(z0) + dot4(z1);
#pragma unroll
    for (int off = 32; off > 0; off >>= 1) ss += __shfl_xor(ss, off);
    __shared__ float wpart[4];
    __shared__ float invz_s;
    if (lane == 0) wpart[wv] = ss;
    __syncthreads();
    if (tid == 0)
        invz_s = 1.f / fmaxf(sqrtf(wpart[0] + wpart[1] + wpart[2] + wpart[3]), 1e-12f);
    __syncthreads();
    const float iz = invz_s;
    ushort4 o0, o1;
    o0.x = f2bf(z0.x * iz); o0.y = f2bf(z0.y * iz);
    o0.z = f2bf(z0.z * iz); o0.w = f2bf(z0.w * iz);
    o1.x = f2bf(z1.x * iz); o1.y = f2bf(z1.y * iz);
    o1.z = f2bf(z1.z * iz); o1.w = f2bf(z1.w * iz);
    ((ushort4*)(zn + (size_t)b * ND))[tid] = o0;
    ((ushort4*)(zn + (size_t)b * ND))[tid + 256] = o1;
}

// ---------------------------------------------------------------------------
// GEMM + fused CE loss, all-bf16 pre-normalized operands.
// Block = 32 rows x 512 cols, 8 waves; wave w owns cols [w*64, w*64+64).
// 4-stage explicit register pipeline (static names): ~24 loads in flight,
// counted vmcnt waits, prefetch distance = 3 K-steps.
#define LDST(sa0, sa1, sb0, sb1, sb2, sb3, KO)                                \
    do { if ((KO) < ND) {                                                     \
        sa0 = *(const bf16x8*)(ap + (KO));                                    \
        sa1 = *(const bf16x8*)(ap + 16 * ND + (KO));                          \
        sb0 = *(const bf16x8*)(bp + (KO));                                    \
        sb1 = *(const bf16x8*)(bp + 16 * ND + (KO));                          \
        sb2 = *(const bf16x8*)(bp + 32 * ND + (KO));                          \
        sb3 = *(const bf16x8*)(bp + 48 * ND + (KO));                          \
    } } while (0)

#define DOMFMA(sa0, sa1, sb0, sb1, sb2, sb3)                                  \
    do {                                                                      \
        acc[0][0] = __builtin_amdgcn_mfma_f32_16x16x32_bf16(sa0, sb0, acc[0][0], 0, 0, 0); \
        acc[1][0] = __builtin_amdgcn_mfma_f32_16x16x32_bf16(sa1, sb0, acc[1][0], 0, 0, 0); \
        acc[0][1] = __builtin_amdgcn_mfma_f32_16x16x32_bf16(sa0, sb1, acc[0][1], 0, 0, 0); \
        acc[1][1] = __builtin_amdgcn_mfma_f32_16x16x32_bf16(sa1, sb1, acc[1][1], 0, 0, 0); \
        acc[0][2] = __builtin_amdgcn_mfma_f32_16x16x32_bf16(sa0, sb2, acc[0][2], 0, 0, 0); \
        acc[1][2] = __builtin_amdgcn_mfma_f32_16x16x32_bf16(sa1, sb2, acc[1][2], 0, 0, 0); \
        acc[0][3] = __builtin_amdgcn_mfma_f32_16x16x32_bf16(sa0, sb3, acc[0][3], 0, 0, 0); \
        acc[1][3] = __builtin_amdgcn_mfma_f32_16x16x32_bf16(sa1, sb3, acc[1][3], 0, 0, 0); \
    } while (0)

__global__ __launch_bounds__(512, 2) void gemm_loss_kernel(
        const unsigned short* __restrict__ an, // [NM][ND] bf16
        const unsigned short* __restrict__ zn, // [NB][ND] bf16
        float* __restrict__ loss_acc) {
    const int tid  = threadIdx.x;
    const int lane = tid & 63;
    const int w    = tid >> 6;
    const int l15  = lane & 15;
    const int l4   = lane >> 4;
    const int brow = blockIdx.x * 32;
    const int bcol = w * 64;

    const short* ap = (const short*)an + (size_t)(brow + l15) * ND + l4 * 8;
    const short* bp = (const short*)zn + (size_t)(bcol + l15) * ND + l4 * 8;

    f32x4 acc[2][4] = {};

    bf16x8 xa0, xa1, xb0, xb1, xb2, xb3;
    bf16x8 ya0, ya1, yb0, yb1, yb2, yb3;
    bf16x8 za0, za1, zb0, zb1, zb2, zb3;
    bf16x8 wa0, wa1, wb0, wb1, wb2, wb3;

    LDST(xa0, xa1, xb0, xb1, xb2, xb3, 0);
    LDST(ya0, ya1, yb0, yb1, yb2, yb3, 32);
    LDST(za0, za1, zb0, zb1, zb2, zb3, 64);
    LDST(wa0, wa1, wb0, wb1, wb2, wb3, 96);

#pragma unroll 16
    for (int it = 0; it < 16; ++it) {
        const int ko = it * 128;
        DOMFMA(xa0, xa1, xb0, xb1, xb2, xb3);
        LDST(xa0, xa1, xb0, xb1, xb2, xb3, ko + 128);
        DOMFMA(ya0, ya1, yb0, yb1, yb2, yb3);
        LDST(ya0, ya1, yb0, yb1, yb2, yb3, ko + 160);
        DOMFMA(za0, za1, zb0, zb1, zb2, zb3);
        LDST(za0, za1, zb0, zb1, zb2, zb3, ko + 192);
        DOMFMA(wa0, wa1, wb0, wb1, wb2, wb3);
        LDST(wa0, wa1, wb0, wb1, wb2, wb3, ko + 224);
    }

    // ---- epilogue: logits = acc * (1/TEMP); per-row logsumexp - pos ----
    __shared__ float sm_max[32][8];
    __shared__ float sm_sum[32][8];
    __shared__ float sm_pos[32];

#pragma unroll
    for (int m = 0; m < 2; ++m) {
#pragma unroll
        for (int r = 0; r < 4; ++r) {
            const int row = m * 16 + l4 * 4 + r;        // local row 0..31
            float lg[4];
            float mx = -1e30f;
#pragma unroll
            for (int n = 0; n < 4; ++n) {
                lg[n] = acc[m][n][r] * 5.0f;            // /TEMP
                mx = fmaxf(mx, lg[n]);
            }
            mx = fmaxf(mx, __shfl_xor(mx, 1));
            mx = fmaxf(mx, __shfl_xor(mx, 2));
            mx = fmaxf(mx, __shfl_xor(mx, 4));
            mx = fmaxf(mx, __shfl_xor(mx, 8));
            float se = 0.f;
#pragma unroll
            for (int n = 0; n < 4; ++n) se += __expf(lg[n] - mx);
            se += __shfl_xor(se, 1);
            se += __shfl_xor(se, 2);
            se += __shfl_xor(se, 4);
            se += __shfl_xor(se, 8);
            if (l15 == 0) { sm_max[row][w] = mx; sm_sum[row][w] = se; }
            const int posc = (brow + row) & (NB - 1);   // global row % 512
#pragma unroll
            for (int n = 0; n < 4; ++n)
                if (bcol + n * 16 + l15 == posc) sm_pos[row] = lg[n];
        }
    }
    __syncthreads();

    if (tid < 32) {
        const int row = tid;
        float gm = -1e30f;
#pragma unroll
        for (int wv = 0; wv < 8; ++wv) gm = fmaxf(gm, sm_max[row][wv]);
        float tot = 0.f;
#pragma unroll
        for (int wv = 0; wv < 8; ++wv)
            tot += sm_sum[row][wv] * __expf(sm_max[row][wv] - gm);
        float term = gm + __logf(tot) - sm_pos[row];
        term += __shfl_xor(term, 16);
        term += __shfl_xor(term, 8);
        term += __shfl_xor(term, 4);
        term += __shfl_xor(term, 2);
        term += __shfl_xor(term, 1);
        if (tid == 0) atomicAdd(loss_acc, term);
    }
}

__global__ void finalize_kernel(const float* __restrict__ acc,
                                float* __restrict__ out) {
    out[0] = acc[0] * (1.0f / (float)NM);
}

extern "C" void kernel_launch(void* const* d_in, const int* in_sizes, int n_in,
                              void* d_out, int out_size, void* d_ws, size_t ws_size,
                              hipStream_t stream) {
    const float* feat = (const float*)d_in[0];

    unsigned short* an = (unsigned short*)d_ws;            // 8192*2048 bf16 = 32 MB
    unsigned short* zn = an + (size_t)NM * ND;             // 512*2048 bf16 = 2 MB
    float* lacc = (float*)(zn + (size_t)NB * ND);          // 1 float

    hipMemsetAsync(lacc, 0, sizeof(float), stream);

    prep_kernel<<<NB, 256, 0, stream>>>(feat, an, zn);
    gemm_loss_kernel<<<NM / 32, 512, 0, stream>>>(an, zn, lacc);
    finalize_kernel<<<1, 1, 0, stream>>>(lacc, (float*)d_out);
}

// Round 5
// 73.551 us; speedup vs baseline: 4.5724x; 1.6094x over previous
//
#include <hip/hip_runtime.h>
#include <hip/hip_bf16.h>
#include <math.h>

#define NP 16
#define NB 512
#define ND 2048
#define NM (NP*NB)          // 8192 rows
#define BK 64
#define NS (ND/BK)          // 32 K-steps

typedef __attribute__((ext_vector_type(8))) short bf16x8;
typedef __attribute__((ext_vector_type(4))) float f32x4;
typedef unsigned int u32;

__device__ inline unsigned short f2bf(float f) {
    unsigned u = __float_as_uint(f);
    unsigned r = (u + 0x7fffu + ((u >> 16) & 1u)) >> 16;   // RNE
    return (unsigned short)r;
}

__device__ inline float dot4(float4 v) {
    return v.x * v.x + v.y * v.y + v.z * v.z + v.w * v.w;
}

// ---------------------------------------------------------------------------
// Prep: one pass over feat -> row-normalized bf16 A + normalized bf16 z row.
__global__ __launch_bounds__(256) void prep_kernel(
        const float* __restrict__ feat,
        unsigned short* __restrict__ an,     // [NM][ND] bf16, row-normalized
        unsigned short* __restrict__ zn) {   // [NB][ND] bf16, row-normalized
    const int b = blockIdx.x, tid = threadIdx.x;
    const int lane = tid & 63, wv = tid >> 6;
    const float4* feat4 = (const float4*)feat;

    float4 zp[8];
#pragma unroll
    for (int it = 0; it < 8; ++it) zp[it] = make_float4(0.f, 0.f, 0.f, 0.f);

#pragma unroll
    for (int j = 0; j < 4; ++j) {
        const int p = wv * 4 + j;
        const size_t row = (size_t)p * NB + b;
        const float4* rp = feat4 + row * (ND / 4);
        float4 rv[8];
        float ss = 0.f;
#pragma unroll
        for (int it = 0; it < 8; ++it) {
            rv[it] = rp[it * 64 + lane];
            ss += dot4(rv[it]);
            zp[it].x += rv[it].x; zp[it].y += rv[it].y;
            zp[it].z += rv[it].z; zp[it].w += rv[it].w;
        }
#pragma unroll
        for (int off = 32; off > 0; off >>= 1) ss += __shfl_xor(ss, off);
        const float inv = 1.f / fmaxf(sqrtf(ss), 1e-12f);
        ushort4* wp = (ushort4*)(an + row * ND);
#pragma unroll
        for (int it = 0; it < 8; ++it) {
            ushort4 o;
            o.x = f2bf(rv[it].x * inv); o.y = f2bf(rv[it].y * inv);
            o.z = f2bf(rv[it].z * inv); o.w = f2bf(rv[it].w * inv);
            wp[it * 64 + lane] = o;
        }
    }

    __shared__ float4 zl[4][512];        // 32 KB
#pragma unroll
    for (int it = 0; it < 8; ++it) zl[wv][it * 64 + lane] = zp[it];
    __syncthreads();

    float4 z0 = zl[0][tid];
    float4 z1 = zl[0][tid + 256];
    {
        float4 a = zl[1][tid], c = zl[2][tid], d = zl[3][tid];
        z0.x += a.x + c.x + d.x; z0.y += a.y + c.y + d.y;
        z0.z += a.z + c.z + d.z; z0.w += a.w + c.w + d.w;
        float4 e = zl[1][tid + 256], f = zl[2][tid + 256], g = zl[3][tid + 256];
        z1.x += e.x + f.x + g.x; z1.y += e.y + f.y + g.y;
        z1.z += e.z + f.z + g.z; z1.w += e.w + f.w + g.w;
    }
    float ss = dot4(z0) + dot4(z1);
#pragma unroll
    for (int off = 32; off > 0; off >>= 1) ss += __shfl_xor(ss, off);
    __shared__ float wpart[4];
    __shared__ float invz_s;
    if (lane == 0) wpart[wv] = ss;
    __syncthreads();
    if (tid == 0)
        invz_s = 1.f / fmaxf(sqrtf(wpart[0] + wpart[1] + wpart[2] + wpart[3]), 1e-12f);
    __syncthreads();
    const float iz = invz_s;
    ushort4 o0, o1;
    o0.x = f2bf(z0.x * iz); o0.y = f2bf(z0.y * iz);
    o0.z = f2bf(z0.z * iz); o0.w = f2bf(z0.w * iz);
    o1.x = f2bf(z1.x * iz); o1.y = f2bf(z1.y * iz);
    o1.z = f2bf(z1.z * iz); o1.w = f2bf(z1.w * iz);
    ((ushort4*)(zn + (size_t)b * ND))[tid] = o0;
    ((ushort4*)(zn + (size_t)b * ND))[tid + 256] = o1;
}

// ---------------------------------------------------------------------------
// GEMM + fused CE loss. Block = 32 rows x 512 cols, 1024 thr = 16 waves
// (4 waves/SIMD). global_load_lds staging (no VGPR round-trip, loads can't be
// sunk by the scheduler), double-buffered LDS, BK=64, 2-phase loop.
// LDS chunk swizzle c' = c ^ (r & 7) applied on BOTH sides: inverse-swizzled
// global source (linear LDS dest, required by global_load_lds) + swizzled
// ds_read address.
__global__ __launch_bounds__(1024, 4) void gemm_loss_kernel(
        const unsigned short* __restrict__ an, // [NM][ND] bf16
        const unsigned short* __restrict__ zn, // [NB][ND] bf16
        float* __restrict__ loss_acc) {
    __shared__ __align__(16) unsigned char bbuf[2][NB * BK * 2];   // 2 x 64 KB
    __shared__ __align__(16) unsigned char abuf[2][32 * BK * 2];   // 2 x 4 KB
    __shared__ float sm_max[32][16];
    __shared__ float sm_sum[32][16];
    __shared__ float sm_pos[32];

    const int tid  = threadIdx.x;
    const int lane = tid & 63;
    const int w    = tid >> 6;       // 0..15
    const int l15  = lane & 15;
    const int l4   = lane >> 4;      // 0..3
    const int brow = blockIdx.x * 32;

    const unsigned char* znb = (const unsigned char*)zn;
    const unsigned char* anb = (const unsigned char*)an;

    f32x4 acc[2][2] = {};

#define STAGE(buf, s) do {                                                    \
        const int koB = (s) * (BK * 2);  /* byte offset along a row */        \
        _Pragma("unroll")                                                     \
        for (int i = 0; i < 4; ++i) {                                         \
            int q = i * 1024 + tid;                                           \
            int r = q >> 3, c = q & 7;                                        \
            int cs = c ^ (r & 7);                                             \
            __builtin_amdgcn_global_load_lds(                                 \
                (const u32*)(znb + (size_t)r * (ND * 2) + koB + cs * 16),     \
                (u32*)(&bbuf[buf][q * 16]), 16, 0, 0);                        \
        }                                                                     \
        if (tid < 256) {                                                      \
            int q = tid;                                                      \
            int r = q >> 3, c = q & 7;                                        \
            int cs = c ^ (r & 7);                                             \
            __builtin_amdgcn_global_load_lds(                                 \
                (const u32*)(anb + (size_t)(brow + r) * (ND * 2) + koB + cs * 16), \
                (u32*)(&abuf[buf][q * 16]), 16, 0, 0);                        \
        }                                                                     \
    } while (0)

#define COMPUTE(buf) do {                                                     \
        bf16x8 afr[2][2], bfr[2][2];                                          \
        _Pragma("unroll")                                                     \
        for (int m = 0; m < 2; ++m)                                           \
        _Pragma("unroll")                                                     \
        for (int kc = 0; kc < 2; ++kc) {                                      \
            int r = m * 16 + l15;                                             \
            int c = kc * 4 + l4;                                              \
            int cs = c ^ (r & 7);                                             \
            afr[m][kc] = *(const bf16x8*)(&abuf[buf][r * 128 + cs * 16]);     \
        }                                                                     \
        _Pragma("unroll")                                                     \
        for (int n = 0; n < 2; ++n)                                           \
        _Pragma("unroll")                                                     \
        for (int kc = 0; kc < 2; ++kc) {                                      \
            int r = w * 32 + n * 16 + l15;                                    \
            int c = kc * 4 + l4;                                              \
            int cs = c ^ (r & 7);                                             \
            bfr[n][kc] = *(const bf16x8*)(&bbuf[buf][r * 128 + cs * 16]);     \
        }                                                                     \
        _Pragma("unroll")                                                     \
        for (int kc = 0; kc < 2; ++kc)                                        \
        _Pragma("unroll")                                                     \
        for (int m = 0; m < 2; ++m)                                           \
        _Pragma("unroll")                                                     \
        for (int n = 0; n < 2; ++n)                                           \
            acc[m][n] = __builtin_amdgcn_mfma_f32_16x16x32_bf16(              \
                afr[m][kc], bfr[n][kc], acc[m][n], 0, 0, 0);                  \
    } while (0)

    STAGE(0, 0);
    __syncthreads();                       // drains vmcnt(0): buf0 ready
    for (int s = 0; s < NS; ++s) {
        if (s + 1 < NS) STAGE((s + 1) & 1, s + 1);   // async, flies under MFMA
        COMPUTE(s & 1);
        __syncthreads();                   // drain staging + all reads done
    }
#undef STAGE
#undef COMPUTE

    // ---- epilogue: logits = acc * (1/TEMP); per-row logsumexp - pos ----
#pragma unroll
    for (int m = 0; m < 2; ++m) {
#pragma unroll
        for (int r = 0; r < 4; ++r) {
            const int row = m * 16 + l4 * 4 + r;        // local row 0..31
            float lg[2];
            float mx = -1e30f;
#pragma unroll
            for (int n = 0; n < 2; ++n) {
                lg[n] = acc[m][n][r] * 5.0f;            // /TEMP
                mx = fmaxf(mx, lg[n]);
            }
            mx = fmaxf(mx, __shfl_xor(mx, 1));
            mx = fmaxf(mx, __shfl_xor(mx, 2));
            mx = fmaxf(mx, __shfl_xor(mx, 4));
            mx = fmaxf(mx, __shfl_xor(mx, 8));
            float se = 0.f;
#pragma unroll
            for (int n = 0; n < 2; ++n) se += __expf(lg[n] - mx);
            se += __shfl_xor(se, 1);
            se += __shfl_xor(se, 2);
            se += __shfl_xor(se, 4);
            se += __shfl_xor(se, 8);
            if (l15 == 0) { sm_max[row][w] = mx; sm_sum[row][w] = se; }
            const int posc = (brow + row) & (NB - 1);   // global row % 512
#pragma unroll
            for (int n = 0; n < 2; ++n)
                if (w * 32 + n * 16 + l15 == posc) sm_pos[row] = lg[n];
        }
    }
    __syncthreads();

    if (tid < 32) {
        const int row = tid;
        float gm = -1e30f;
#pragma unroll
        for (int wv = 0; wv < 16; ++wv) gm = fmaxf(gm, sm_max[row][wv]);
        float tot = 0.f;
#pragma unroll
        for (int wv = 0; wv < 16; ++wv)
            tot += sm_sum[row][wv] * __expf(sm_max[row][wv] - gm);
        float term = gm + __logf(tot) - sm_pos[row];
        term += __shfl_xor(term, 16);
        term += __shfl_xor(term, 8);
        term += __shfl_xor(term, 4);
        term += __shfl_xor(term, 2);
        term += __shfl_xor(term, 1);
        if (tid == 0) atomicAdd(loss_acc, term);
    }
}

__global__ void finalize_kernel(const float* __restrict__ acc,
                                float* __restrict__ out) {
    out[0] = acc[0] * (1.0f / (float)NM);
}

extern "C" void kernel_launch(void* const* d_in, const int* in_sizes, int n_in,
                              void* d_out, int out_size, void* d_ws, size_t ws_size,
                              hipStream_t stream) {
    const float* feat = (const float*)d_in[0];

    unsigned short* an = (unsigned short*)d_ws;            // 8192*2048 bf16 = 32 MB
    unsigned short* zn = an + (size_t)NM * ND;             // 512*2048 bf16 = 2 MB
    float* lacc = (float*)(zn + (size_t)NB * ND);          // 1 float

    hipMemsetAsync(lacc, 0, sizeof(float), stream);

    prep_kernel<<<NB, 256, 0, stream>>>(feat, an, zn);
    gemm_loss_kernel<<<NM / 32, 1024, 0, stream>>>(an, zn, lacc);
    finalize_kernel<<<1, 1, 0, stream>>>(lacc, (float*)d_out);
}

// Round 6
// 72.180 us; speedup vs baseline: 4.6592x; 1.0190x over previous
//
#include <hip/hip_runtime.h>
#include <hip/hip_bf16.h>
#include <math.h>

#define NP 16
#define NB 512
#define ND 2048
#define NM (NP*NB)          // 8192 rows
#define BK 64
#define NS (ND/BK)          // 32 K-steps

typedef __attribute__((ext_vector_type(8))) short bf16x8;
typedef __attribute__((ext_vector_type(4))) float f32x4;
typedef unsigned int u32;

__device__ inline unsigned short f2bf(float f) {
    unsigned u = __float_as_uint(f);
    unsigned r = (u + 0x7fffu + ((u >> 16) & 1u)) >> 16;   // RNE
    return (unsigned short)r;
}

__device__ inline float dot4(float4 v) {
    return v.x * v.x + v.y * v.y + v.z * v.z + v.w * v.w;
}

// ---------------------------------------------------------------------------
// Prep: one pass over feat -> row-normalized bf16 A + normalized bf16 z row.
__global__ __launch_bounds__(256) void prep_kernel(
        const float* __restrict__ feat,
        unsigned short* __restrict__ an,     // [NM][ND] bf16, row-normalized
        unsigned short* __restrict__ zn) {   // [NB][ND] bf16, row-normalized
    const int b = blockIdx.x, tid = threadIdx.x;
    const int lane = tid & 63, wv = tid >> 6;
    const float4* feat4 = (const float4*)feat;

    float4 zp[8];
#pragma unroll
    for (int it = 0; it < 8; ++it) zp[it] = make_float4(0.f, 0.f, 0.f, 0.f);

#pragma unroll
    for (int j = 0; j < 4; ++j) {
        const int p = wv * 4 + j;
        const size_t row = (size_t)p * NB + b;
        const float4* rp = feat4 + row * (ND / 4);
        float4 rv[8];
        float ss = 0.f;
#pragma unroll
        for (int it = 0; it < 8; ++it) {
            rv[it] = rp[it * 64 + lane];
            ss += dot4(rv[it]);
            zp[it].x += rv[it].x; zp[it].y += rv[it].y;
            zp[it].z += rv[it].z; zp[it].w += rv[it].w;
        }
#pragma unroll
        for (int off = 32; off > 0; off >>= 1) ss += __shfl_xor(ss, off);
        const float inv = 1.f / fmaxf(sqrtf(ss), 1e-12f);
        ushort4* wp = (ushort4*)(an + row * ND);
#pragma unroll
        for (int it = 0; it < 8; ++it) {
            ushort4 o;
            o.x = f2bf(rv[it].x * inv); o.y = f2bf(rv[it].y * inv);
            o.z = f2bf(rv[it].z * inv); o.w = f2bf(rv[it].w * inv);
            wp[it * 64 + lane] = o;
        }
    }

    __shared__ float4 zl[4][512];        // 32 KB
#pragma unroll
    for (int it = 0; it < 8; ++it) zl[wv][it * 64 + lane] = zp[it];
    __syncthreads();

    float4 z0 = zl[0][tid];
    float4 z1 = zl[0][tid + 256];
    {
        float4 a = zl[1][tid], c = zl[2][tid], d = zl[3][tid];
        z0.x += a.x + c.x + d.x; z0.y += a.y + c.y + d.y;
        z0.z += a.z + c.z + d.z; z0.w += a.w + c.w + d.w;
        float4 e = zl[1][tid + 256], f = zl[2][tid + 256], g = zl[3][tid + 256];
        z1.x += e.x + f.x + g.x; z1.y += e.y + f.y + g.y;
        z1.z += e.z + f.z + g.z; z1.w += e.w + f.w + g.w;
    }
    float ss = dot4(z0) + dot4(z1);
#pragma unroll
    for (int off = 32; off > 0; off >>= 1) ss += __shfl_xor(ss, off);
    __shared__ float wpart[4];
    __shared__ float invz_s;
    if (lane == 0) wpart[wv] = ss;
    __syncthreads();
    if (tid == 0)
        invz_s = 1.f / fmaxf(sqrtf(wpart[0] + wpart[1] + wpart[2] + wpart[3]), 1e-12f);
    __syncthreads();
    const float iz = invz_s;
    ushort4 o0, o1;
    o0.x = f2bf(z0.x * iz); o0.y = f2bf(z0.y * iz);
    o0.z = f2bf(z0.z * iz); o0.w = f2bf(z0.w * iz);
    o1.x = f2bf(z1.x * iz); o1.y = f2bf(z1.y * iz);
    o1.z = f2bf(z1.z * iz); o1.w = f2bf(z1.w * iz);
    ((ushort4*)(zn + (size_t)b * ND))[tid] = o0;
    ((ushort4*)(zn + (size_t)b * ND))[tid + 256] = o1;
}

// ---------------------------------------------------------------------------
// GEMM + fused CE loss. Block = 32 rows x 512 cols, 1024 thr = 16 waves.
// Counted-vmcnt 2-deep pipeline (T3+T4): raw s_barrier (no implicit vmcnt
// drain), per-wave counted s_waitcnt, STAGE issued right before the MFMA
// cluster so loads fly under compute. A is staged in 2 copies by waves 0-7
// (5 loads/thr/stage) so vmcnt counts stay wave-uniform; waves 8-15 do 4.
__global__ __launch_bounds__(1024, 4) void gemm_loss_kernel(
        const unsigned short* __restrict__ an, // [NM][ND] bf16
        const unsigned short* __restrict__ zn, // [NB][ND] bf16
        float* __restrict__ loss_acc) {
    __shared__ __align__(16) unsigned char bbuf[2][NB * BK * 2];   // 2 x 64 KB
    __shared__ __align__(16) unsigned char abuf[2][2 * 32 * BK * 2]; // 2 x 8 KB
    __shared__ float sm_max[32][16];
    __shared__ float sm_sum[32][16];
    __shared__ float sm_pos[32];

    const int tid  = threadIdx.x;
    const int lane = tid & 63;
    const int w    = tid >> 6;       // 0..15
    const int l15  = lane & 15;
    const int l4   = lane >> 4;      // 0..3
    const int brow = blockIdx.x * 32;

    const unsigned char* znb = (const unsigned char*)zn;
    const unsigned char* anb = (const unsigned char*)an;

    f32x4 acc[2][2] = {};

#define STAGE(buf, s) do {                                                    \
        const int koB = (s) * (BK * 2);  /* byte offset along a row */        \
        _Pragma("unroll")                                                     \
        for (int i = 0; i < 4; ++i) {                                         \
            int q = i * 1024 + tid;                                           \
            int r = q >> 3, c = q & 7;                                        \
            int cs = c ^ (r & 7);                                             \
            __builtin_amdgcn_global_load_lds(                                 \
                (const u32*)(znb + (size_t)r * (ND * 2) + koB + cs * 16),     \
                (u32*)(&bbuf[buf][q * 16]), 16, 0, 0);                        \
        }                                                                     \
        if (tid < 512) {  /* waves 0-7: 2 copies of the 32x64 A tile */       \
            int chunk = tid & 255;                                            \
            int r = chunk >> 3, c = chunk & 7;                                \
            int cs = c ^ (r & 7);                                             \
            __builtin_amdgcn_global_load_lds(                                 \
                (const u32*)(anb + (size_t)(brow + r) * (ND * 2) + koB + cs * 16), \
                (u32*)(&abuf[buf][tid * 16]), 16, 0, 0);                      \
        }                                                                     \
    } while (0)

    STAGE(0, 0);
    STAGE(1, 1);

    const int acopy = (w >> 3) * 4096;   // waves 0-7 read copy 0, 8-15 copy 1

    for (int s = 0; s < NS; ++s) {
        // ---- wait for stage s (counted: stage s+1 stays in flight) ----
        if (s + 1 < NS) {
            if (w < 8) asm volatile("s_waitcnt vmcnt(5)" ::: "memory");
            else       asm volatile("s_waitcnt vmcnt(4)" ::: "memory");
        } else {
            asm volatile("s_waitcnt vmcnt(0)" ::: "memory");
        }
        __builtin_amdgcn_sched_barrier(0);
        __builtin_amdgcn_s_barrier();            // buf[s&1] fully staged

        const int buf = s & 1;
        bf16x8 afr[2][2], bfr[2][2];
#pragma unroll
        for (int m = 0; m < 2; ++m)
#pragma unroll
        for (int kc = 0; kc < 2; ++kc) {
            int r = m * 16 + l15;
            int c = kc * 4 + l4;
            int cs = c ^ (r & 7);
            afr[m][kc] = *(const bf16x8*)(&abuf[buf][acopy + r * 128 + cs * 16]);
        }
#pragma unroll
        for (int n = 0; n < 2; ++n)
#pragma unroll
        for (int kc = 0; kc < 2; ++kc) {
            int r = w * 32 + n * 16 + l15;
            int c = kc * 4 + l4;
            int cs = c ^ (r & 7);
            bfr[n][kc] = *(const bf16x8*)(&bbuf[buf][r * 128 + cs * 16]);
        }
        __builtin_amdgcn_sched_barrier(0);
        asm volatile("s_waitcnt lgkmcnt(0)" ::: "memory");  // my reads done
        __builtin_amdgcn_sched_barrier(0);
        __builtin_amdgcn_s_barrier();            // all waves done reading

        if (s + 2 < NS) STAGE(buf, s + 2);       // overwrite old buf, fly under MFMA

        __builtin_amdgcn_s_setprio(1);
#pragma unroll
        for (int kc = 0; kc < 2; ++kc)
#pragma unroll
        for (int m = 0; m < 2; ++m)
#pragma unroll
        for (int n = 0; n < 2; ++n)
            acc[m][n] = __builtin_amdgcn_mfma_f32_16x16x32_bf16(
                afr[m][kc], bfr[n][kc], acc[m][n], 0, 0, 0);
        __builtin_amdgcn_s_setprio(0);
    }
#undef STAGE

    // ---- epilogue: logits = acc * (1/TEMP); per-row logsumexp - pos ----
#pragma unroll
    for (int m = 0; m < 2; ++m) {
#pragma unroll
        for (int r = 0; r < 4; ++r) {
            const int row = m * 16 + l4 * 4 + r;        // local row 0..31
            float lg[2];
            float mx = -1e30f;
#pragma unroll
            for (int n = 0; n < 2; ++n) {
                lg[n] = acc[m][n][r] * 5.0f;            // /TEMP
                mx = fmaxf(mx, lg[n]);
            }
            mx = fmaxf(mx, __shfl_xor(mx, 1));
            mx = fmaxf(mx, __shfl_xor(mx, 2));
            mx = fmaxf(mx, __shfl_xor(mx, 4));
            mx = fmaxf(mx, __shfl_xor(mx, 8));
            float se = 0.f;
#pragma unroll
            for (int n = 0; n < 2; ++n) se += __expf(lg[n] - mx);
            se += __shfl_xor(se, 1);
            se += __shfl_xor(se, 2);
            se += __shfl_xor(se, 4);
            se += __shfl_xor(se, 8);
            if (l15 == 0) { sm_max[row][w] = mx; sm_sum[row][w] = se; }
            const int posc = (brow + row) & (NB - 1);   // global row % 512
#pragma unroll
            for (int n = 0; n < 2; ++n)
                if (w * 32 + n * 16 + l15 == posc) sm_pos[row] = lg[n];
        }
    }
    __syncthreads();

    if (tid < 32) {
        const int row = tid;
        float gm = -1e30f;
#pragma unroll
        for (int wv = 0; wv < 16; ++wv) gm = fmaxf(gm, sm_max[row][wv]);
        float tot = 0.f;
#pragma unroll
        for (int wv = 0; wv < 16; ++wv)
            tot += sm_sum[row][wv] * __expf(sm_max[row][wv] - gm);
        float term = gm + __logf(tot) - sm_pos[row];
        term += __shfl_xor(term, 16);
        term += __shfl_xor(term, 8);
        term += __shfl_xor(term, 4);
        term += __shfl_xor(term, 2);
        term += __shfl_xor(term, 1);
        if (tid == 0) atomicAdd(loss_acc, term);
    }
}

__global__ void finalize_kernel(const float* __restrict__ acc,
                                float* __restrict__ out) {
    out[0] = acc[0] * (1.0f / (float)NM);
}

extern "C" void kernel_launch(void* const* d_in, const int* in_sizes, int n_in,
                              void* d_out, int out_size, void* d_ws, size_t ws_size,
                              hipStream_t stream) {
    const float* feat = (const float*)d_in[0];

    unsigned short* an = (unsigned short*)d_ws;            // 8192*2048 bf16 = 32 MB
    unsigned short* zn = an + (size_t)NM * ND;             // 512*2048 bf16 = 2 MB
    float* lacc = (float*)(zn + (size_t)NB * ND);          // 1 float

    hipMemsetAsync(lacc, 0, sizeof(float), stream);

    prep_kernel<<<NB, 256, 0, stream>>>(feat, an, zn);
    gemm_loss_kernel<<<NM / 32, 1024, 0, stream>>>(an, zn, lacc);
    finalize_kernel<<<1, 1, 0, stream>>>(lacc, (float*)d_out);
}